// Round 7
// baseline (230.046 us; speedup 1.0000x reference)
//
#include <hip/hip_runtime.h>
#include <math.h>
#include <stdint.h>

// 1D grayscale dilation (max-plus conv), K=11, halo=5, fp32.
// out[i] = max_j ( x[i-5+j] + h[j] ),  h[j] = -(j-5)^2 / (4*scale)
//
// R4 (LDS tile) 81.7us, R5 (shuffles) 80.5us, R6 (direct global) 81.6us,
// R8 (pin) 79.4us, R9 (global_load_lds staging, no VGPR dest -> nothing to
// serialize) 80.1us: FIVE structures, identical time. MLP theory dead.
//   Revised model: per-CU outstanding-read cap (~30 lines, TCP/MSHR) x
//   latency bounds read BW. 2.5 TB/s / 256 CU at ~900cy HBM latency
//   = ~3.7 KB in flight/CU -- matches. Structure can't help; only LOWER
//   LATENCY can (L3 hits ~ half latency -> ~2x read BW at same depth).
//   Counters show FETCH=68MB on a 134MB input: half the input IS already
//   L3-resident each iteration, but our write-allocating stores push
//   134MB of output into L3 mid-kernel, evicting the input's tail
//   (134+134 > 256MiB L3). We halve our own hit rate every iteration.
// R10 (this): __builtin_nontemporal_store on the output stream (the fill
//   kernel evidently streams the same way to hit 6.7 TB/s). Input stays
//   fully L3-resident across iterations -> reads mostly L3 hits.
//   Signature: FETCH_SIZE 66590 KB -> <=30000 KB. Everything else = R9.

typedef float f32x4 __attribute__((ext_vector_type(4)));

#define BLOCK   256
#define QPT     4                      // output quads per thread
#define TILE_Q  (BLOCK * QPT)          // 1024 quads per block
#define HALO_Q  2                      // staged halo quads each side
#define STAGE_Q (TILE_Q + 2 * HALO_Q)  // 1028 quads = 16448 B LDS

// Direct global->LDS 16B load. LDS dest = wave-uniform base + lane*16 (HW);
// global src is per-lane. AS casts via uintptr (LDS aperture 4GiB-aligned).
__device__ __forceinline__ void gload_lds16(const f32x4* g, f32x4* l) {
    __builtin_amdgcn_global_load_lds(
        (const __attribute__((address_space(1))) uint32_t*)(uintptr_t)g,
        (__attribute__((address_space(3))) uint32_t*)(uintptr_t)l,
        16, 0, 0);
}

__global__ __launch_bounds__(BLOCK) void dilate1d_kernel(
    const f32x4* __restrict__ x4,
    const float* __restrict__ scale_p,
    f32x4*       __restrict__ out4,
    int n4)   // number of float4 elements in x / out
{
    __shared__ f32x4 smem[STAGE_Q];

    const float NEG  = -INFINITY;
    const f32x4 NEG4 = {NEG, NEG, NEG, NEG};

    const int Q0   = blockIdx.x * TILE_Q;        // first output quad of tile
    const int g0   = Q0 - HALO_Q;                // first staged quad (global)
    const int wid  = threadIdx.x >> 6;           // wave id (uniform per wave)

    // ---- stage tile + halo into LDS, direct-to-LDS (no VGPR round-trip) ----
    const bool interior = (g0 >= 0) && (g0 + STAGE_Q <= n4);
    if (interior) {
#pragma unroll
        for (int t = 0; t < QPT; ++t) {
            int idx = t * BLOCK + threadIdx.x;            // per-lane global
            gload_lds16(x4 + g0 + idx,                    // per-lane src
                        smem + t * BLOCK + wid * 64);     // wave-uniform dst
        }
        if (threadIdx.x < 2 * HALO_Q) {                   // lanes 0..3, wave 0
            gload_lds16(x4 + g0 + TILE_Q + threadIdx.x,
                        smem + TILE_Q);                   // wave-uniform dst
        }
    } else {
        // only blocks 0 and gridDim-1 take this path
#pragma unroll
        for (int t = 0; t <= QPT; ++t) {
            int idx = threadIdx.x + t * BLOCK;
            if (idx < STAGE_Q) {
                int g = g0 + idx;
                smem[idx] = (g >= 0 && g < n4) ? x4[g] : NEG4;
            }
        }
    }
    __syncthreads();   // drains vmcnt(0): LDS guaranteed filled

    // ---- structuring element: hp[d] = -d^2/(4s) ----
    const float r4s = 1.0f / (4.0f * scale_p[0]);
    const float hp1 = -1.0f  * r4s;
    const float hp2 = -4.0f  * r4s;
    const float hp3 = -9.0f  * r4s;
    const float hp4 = -16.0f * r4s;
    const float hp5 = -25.0f * r4s;

    // ---- compute: block-strided quads (lane-contiguous LDS reads/stores) ----
#pragma unroll
    for (int t = 0; t < QPT; ++t) {
        int idx = threadIdx.x + t * BLOCK;       // tile-local quad
        int q   = Q0 + idx;                      // global output quad
        if (q >= n4) break;

        // w[k] = x[4*q + k - 8], k = 0..19  (5 consecutive ds_read_b128)
        float w[20];
#pragma unroll
        for (int r = 0; r < 5; ++r) {
            f32x4 v = smem[idx + r];             // staged quad (idx+HALO_Q)-2+r
            w[4 * r + 0] = v.x;
            w[4 * r + 1] = v.y;
            w[4 * r + 2] = v.z;
            w[4 * r + 3] = v.w;
        }

        f32x4 o;
#pragma unroll
        for (int i = 0; i < 4; ++i) {
            int c = 8 + i;                       // center of window in w
            float m = w[c];                      // hp[0] == 0
            m = fmaxf(m, hp1 + fmaxf(w[c - 1], w[c + 1]));
            m = fmaxf(m, hp2 + fmaxf(w[c - 2], w[c + 2]));
            m = fmaxf(m, hp3 + fmaxf(w[c - 3], w[c + 3]));
            m = fmaxf(m, hp4 + fmaxf(w[c - 4], w[c + 4]));
            m = fmaxf(m, hp5 + fmaxf(w[c - 5], w[c + 5]));
            o[i] = m;
        }
        // Nontemporal: no L2/L3 allocation for the write-once output stream.
        // Keeps the 134MB input L3-resident across bench iterations.
        __builtin_nontemporal_store(o, out4 + q);
    }
}

extern "C" void kernel_launch(void* const* d_in, const int* in_sizes, int n_in,
                              void* d_out, int out_size, void* d_ws, size_t ws_size,
                              hipStream_t stream) {
    const float* x       = (const float*)d_in[0];
    const float* scale_p = (const float*)d_in[1];
    float*       out     = (float*)d_out;

    int n  = in_sizes[0];
    int n4 = n / 4;                              // n = 2^25 -> n4 = 2^23

    int grid = (n4 + TILE_Q - 1) / TILE_Q;       // 8192 blocks

    dilate1d_kernel<<<grid, BLOCK, 0, stream>>>(
        (const f32x4*)x, scale_p, (f32x4*)out, n4);
}